// Round 1
// baseline (1202.934 us; speedup 1.0000x reference)
//
#include <hip/hip_runtime.h>
#include <hip/hip_bf16.h>
#include <math.h>

// ---------------------------------------------------------------------------
// Generic tiled fp32 GEMM:  C[M,N] = A[M,K] @ W[N,K]^T  (both K-contiguous)
// Optional epilogue: C = relu((C + bias - m) * (g*rsqrt(v+eps)) + b)
// Requires M%64==0, N%64==0, K%16==0 (true for every GEMM in this net).
// ---------------------------------------------------------------------------
#define BM 64
#define BN 64
#define BK 16

__global__ __launch_bounds__(256)
void gemm_nt(const float* __restrict__ A, const float* __restrict__ W,
             float* __restrict__ C, int M, int N, int K,
             const float* __restrict__ bias,
             const float* __restrict__ bn_g, const float* __restrict__ bn_b,
             const float* __restrict__ bn_m, const float* __restrict__ bn_v,
             int fuse_bn_relu)
{
    __shared__ float As[BK][BM + 4];
    __shared__ float Ws[BK][BN + 4];

    const int tid = threadIdx.x;
    const int tx = tid & 15;        // 0..15  -> N direction (4 cols each)
    const int ty = tid >> 4;        // 0..15  -> M direction (4 rows each)
    const int row0 = blockIdx.y * BM;
    const int col0 = blockIdx.x * BN;

    // staging indices: 4 threads per row, float4 along K
    const int lr = tid >> 2;        // 0..63 row within tile
    const int lk = (tid & 3) * 4;   // 0,4,8,12

    float acc[4][4] = {};

    for (int k0 = 0; k0 < K; k0 += BK) {
        const float4 av = *(const float4*)(A + (size_t)(row0 + lr) * K + k0 + lk);
        const float4 wv = *(const float4*)(W + (size_t)(col0 + lr) * K + k0 + lk);
        As[lk + 0][lr] = av.x; As[lk + 1][lr] = av.y;
        As[lk + 2][lr] = av.z; As[lk + 3][lr] = av.w;
        Ws[lk + 0][lr] = wv.x; Ws[lk + 1][lr] = wv.y;
        Ws[lk + 2][lr] = wv.z; Ws[lk + 3][lr] = wv.w;
        __syncthreads();

        #pragma unroll
        for (int k = 0; k < BK; ++k) {
            float a[4], b[4];
            #pragma unroll
            for (int i = 0; i < 4; ++i) a[i] = As[k][ty * 4 + i];
            #pragma unroll
            for (int j = 0; j < 4; ++j) b[j] = Ws[k][tx * 4 + j];
            #pragma unroll
            for (int i = 0; i < 4; ++i)
                #pragma unroll
                for (int j = 0; j < 4; ++j)
                    acc[i][j] = fmaf(a[i], b[j], acc[i][j]);
        }
        __syncthreads();
    }

    #pragma unroll
    for (int j = 0; j < 4; ++j) {
        const int col = col0 + tx * 4 + j;
        float add = bias ? bias[col] : 0.f;
        float scale = 1.f, shift = 0.f;
        if (fuse_bn_relu) {
            scale = bn_g[col] * rsqrtf(bn_v[col] + 1e-5f);
            shift = bn_b[col] - bn_m[col] * scale;
        }
        #pragma unroll
        for (int i = 0; i < 4; ++i) {
            const int row = row0 + ty * 4 + i;
            float v = acc[i][j] + add;
            if (fuse_bn_relu) v = fmaxf(v * scale + shift, 0.f);
            C[(size_t)row * N + col] = v;
        }
    }
}

// ---------------------------------------------------------------------------
// Fused attention: per batch row b (block), build x[10][688] in LDS from the
// three MLP outputs + bbox + word_embedding, apply channel attention
// (CBAM over N=10), spatial attention (conv1d k=7 over 688), and reduce over
// N. Writes xsum[b][688].
// ---------------------------------------------------------------------------
__global__ __launch_bounds__(256)
void attn_kernel(const float* __restrict__ obj, const float* __restrict__ bbox,
                 const float* __restrict__ word, const float* __restrict__ sen,
                 const float* __restrict__ bod,
                 const float* __restrict__ Wc1, const float* __restrict__ Wc2,
                 const float* __restrict__ Wsa,
                 float* __restrict__ xsum_out)
{
    const int b = blockIdx.x;
    const int tid = threadIdx.x;

    __shared__ float xs[10][688];
    __shared__ float s0[688], s1[688];
    __shared__ float avec[10], mvec[10], att[10];
    __shared__ float cw[14], c1[50], c2[50];

    if (tid < 14) cw[tid] = Wsa[tid];
    if (tid < 50) { c1[tid] = Wc1[tid]; c2[tid] = Wc2[tid]; }

    // ---- gather x = concat(obj, bbox, word, sen, bod) ----
    for (int n = 0; n < 10; ++n) {
        const float* o  = obj  + ((size_t)b * 10 + n) * 128;
        const float* bx = bbox + ((size_t)b * 10 + n) * 4;
        const float* w  = word + ((size_t)b * 10 + n) * 300;
        const float* s  = sen  + ((size_t)b * 10 + n) * 128;
        const float* bo = bod  + (size_t)b * 128;          // broadcast over n
        for (int c = tid; c < 688; c += 256) {
            float v;
            if      (c < 128) v = o[c];
            else if (c < 132) v = bx[c - 128];
            else if (c < 432) v = w[c - 132];
            else if (c < 560) v = s[c - 432];
            else              v = bo[c - 560];
            xs[n][c] = v;
        }
    }
    __syncthreads();

    // ---- channel attention stats: mean & max over feature axis ----
    if (tid < 10) {
        float sm = 0.f, mx = -INFINITY;
        for (int c = 0; c < 688; ++c) {
            float v = xs[tid][c];
            sm += v; mx = fmaxf(mx, v);
        }
        avec[tid] = sm * (1.f / 688.f);
        mvec[tid] = mx;
    }
    __syncthreads();

    if (tid == 0) {
        float ha[5], hm[5];
        #pragma unroll
        for (int i = 0; i < 5; ++i) {
            float sa_ = 0.f, sm_ = 0.f;
            #pragma unroll
            for (int j = 0; j < 10; ++j) {
                sa_ += c1[i * 10 + j] * avec[j];
                sm_ += c1[i * 10 + j] * mvec[j];
            }
            ha[i] = fmaxf(sa_, 0.f);
            hm[i] = fmaxf(sm_, 0.f);
        }
        #pragma unroll
        for (int j = 0; j < 10; ++j) {
            float v = 0.f;
            #pragma unroll
            for (int i = 0; i < 5; ++i) v += c2[j * 5 + i] * (ha[i] + hm[i]);
            att[j] = 1.f / (1.f + expf(-v));
        }
    }
    __syncthreads();

    // ---- apply channel attention; spatial stats (mean/max over N) ----
    for (int c = tid; c < 688; c += 256) {
        float sm = 0.f, mx = -INFINITY;
        #pragma unroll
        for (int n = 0; n < 10; ++n) {
            float v = xs[n][c] * att[n];
            xs[n][c] = v;
            sm += v; mx = fmaxf(mx, v);
        }
        s0[c] = sm * 0.1f;   // mean over N=10
        s1[c] = mx;
    }
    __syncthreads();

    // ---- spatial conv(k=7, pad=3) -> sigmoid -> weighted sum over N ----
    for (int c = tid; c < 688; c += 256) {
        float sa = 0.f;
        #pragma unroll
        for (int j = 0; j < 7; ++j) {
            int cc = c + j - 3;
            if (cc >= 0 && cc < 688)
                sa += cw[j] * s0[cc] + cw[7 + j] * s1[cc];
        }
        float sig = 1.f / (1.f + expf(-sa));
        float sm = 0.f;
        #pragma unroll
        for (int n = 0; n < 10; ++n) sm += xs[n][c];
        xsum_out[(size_t)b * 688 + c] = sm * sig;
    }
}

// ---------------------------------------------------------------------------
extern "C" void kernel_launch(void* const* d_in, const int* in_sizes, int n_in,
                              void* d_out, int out_size, void* d_ws, size_t ws_size,
                              hipStream_t stream)
{
    const float* f_obj = (const float*)d_in[0];
    const float* bbox  = (const float*)d_in[1];
    const float* word  = (const float*)d_in[2];
    const float* sent  = (const float*)d_in[3];
    const float* body  = (const float*)d_in[4];
    const float* W1_o  = (const float*)d_in[5];
    const float* g_o = (const float*)d_in[6],  *b_o = (const float*)d_in[7];
    const float* m_o = (const float*)d_in[8],  *v_o = (const float*)d_in[9];
    const float* W2_o  = (const float*)d_in[10];
    const float* W1_s  = (const float*)d_in[11];
    const float* g_s = (const float*)d_in[12], *b_s = (const float*)d_in[13];
    const float* m_s = (const float*)d_in[14], *v_s = (const float*)d_in[15];
    const float* W2_s  = (const float*)d_in[16];
    const float* W1_b  = (const float*)d_in[17];
    const float* g_b = (const float*)d_in[18], *b_b = (const float*)d_in[19];
    const float* m_b = (const float*)d_in[20], *v_b = (const float*)d_in[21];
    const float* W2_b  = (const float*)d_in[22];
    const float* Wc1 = (const float*)d_in[23];
    const float* Wc2 = (const float*)d_in[24];
    const float* Wsa = (const float*)d_in[25];
    const float* Wf  = (const float*)d_in[26];
    const float* bf  = (const float*)d_in[27];
    const float* g_f = (const float*)d_in[28], *b_f = (const float*)d_in[29];
    const float* m_f = (const float*)d_in[30], *v_f = (const float*)d_in[31];
    float* out = (float*)d_out;

    // workspace layout (floats): total 8,699,904 floats = 34.8 MB
    float* ws   = (float*)d_ws;
    float* sen  = ws;                        // 10240*128
    float* obj  = sen  + 10240 * 128;        // 10240*128
    float* bod  = obj  + 10240 * 128;        // 1024*128
    float* xsum = bod  + 1024 * 128;         // 1024*688
    float* scr  = xsum + 1024 * 688;         // 10240*512 (reused 3x)

    // sentiment MLP: 4096 -> 512 (BN+ReLU) -> 128
    gemm_nt<<<dim3(512 / BN, 10240 / BM), 256, 0, stream>>>(
        sent, W1_s, scr, 10240, 512, 4096, nullptr, g_s, b_s, m_s, v_s, 1);
    gemm_nt<<<dim3(128 / BN, 10240 / BM), 256, 0, stream>>>(
        scr, W2_s, sen, 10240, 128, 512, nullptr, nullptr, nullptr, nullptr, nullptr, 0);

    // object MLP: 1024 -> 128 (BN+ReLU) -> 128
    gemm_nt<<<dim3(128 / BN, 10240 / BM), 256, 0, stream>>>(
        f_obj, W1_o, scr, 10240, 128, 1024, nullptr, g_o, b_o, m_o, v_o, 1);
    gemm_nt<<<dim3(128 / BN, 10240 / BM), 256, 0, stream>>>(
        scr, W2_o, obj, 10240, 128, 128, nullptr, nullptr, nullptr, nullptr, nullptr, 0);

    // body MLP: 2048 -> 256 (BN+ReLU) -> 128   (per-B, broadcast over N later)
    gemm_nt<<<dim3(256 / BN, 1024 / BM), 256, 0, stream>>>(
        body, W1_b, scr, 1024, 256, 2048, nullptr, g_b, b_b, m_b, v_b, 1);
    gemm_nt<<<dim3(128 / BN, 1024 / BM), 256, 0, stream>>>(
        scr, W2_b, bod, 1024, 128, 256, nullptr, nullptr, nullptr, nullptr, nullptr, 0);

    // fused channel+spatial attention + sum over N -> xsum[1024,688]
    attn_kernel<<<1024, 256, 0, stream>>>(obj, bbox, word, sen, bod,
                                          Wc1, Wc2, Wsa, xsum);

    // fc1 + BN + ReLU -> out[1024,256]
    gemm_nt<<<dim3(256 / BN, 1024 / BM), 256, 0, stream>>>(
        xsum, Wf, out, 1024, 256, 688, bf, g_f, b_f, m_f, v_f, 1);
}

// Round 2
// 651.983 us; speedup vs baseline: 1.8450x; 1.8450x over previous
//
#include <hip/hip_runtime.h>
#include <hip/hip_bf16.h>
#include <math.h>

typedef __attribute__((ext_vector_type(8))) short short8;   // 8 x bf16 (4 VGPRs)
typedef __attribute__((ext_vector_type(4))) float floatx4;  // MFMA C/D frag

static __device__ __forceinline__ unsigned short f2bf(float f) {
    unsigned int u = __float_as_uint(f);
    unsigned int r = (u + 0x7fffu + ((u >> 16) & 1u)) >> 16;   // RNE
    return (unsigned short)r;
}

// async 16B global -> LDS copy (lds dest = wave-uniform base + lane*16)
static __device__ __forceinline__ void g2l16(const void* g, void* l) {
    __builtin_amdgcn_global_load_lds(
        (const __attribute__((address_space(1))) unsigned int*)g,
        (__attribute__((address_space(3))) unsigned int*)l,
        16, 0, 0);
}

// ---------------------------------------------------------------------------
// bf16 MFMA GEMM:  C[M,N] = A[M,K] @ W[N,K]^T, A/W bf16 (K-contiguous),
// epilogue: v = acc (+bias); if fuse: v = relu(v*scale+shift) with BN params.
// Writes Cf (fp32) and/or Cb (bf16), either may be null.
// Requires M%128==0, N%128==0, K%32==0.
// 128x128 tile, 4 waves, each wave does a 64x64 quadrant via 4x4 grid of
// 16x16x32 MFMAs. LDS tiles 128x32 bf16 row-major (stride 32, no pad — the
// global_load_lds lane order requires contiguity).
// ---------------------------------------------------------------------------
__global__ __launch_bounds__(256)
void gemm_mfma(const unsigned short* __restrict__ A,
               const unsigned short* __restrict__ W,
               int M, int N, int K,
               float* __restrict__ Cf, unsigned short* __restrict__ Cb,
               const float* __restrict__ bias,
               const float* __restrict__ bn_g, const float* __restrict__ bn_b,
               const float* __restrict__ bn_m, const float* __restrict__ bn_v,
               int fuse_bn_relu)
{
    __shared__ unsigned short As[128 * 32];
    __shared__ unsigned short Bs[128 * 32];

    const int tid  = threadIdx.x;
    const int wave = tid >> 6;
    const int lane = tid & 63;
    const int qd   = lane >> 4;     // quad 0..3
    const int ln   = lane & 15;

    const int row0 = blockIdx.y * 128;
    const int col0 = blockIdx.x * 128;
    const int wr   = (wave >> 1) * 64;   // wave's 64x64 quadrant
    const int wc   = (wave & 1) * 64;

    // staging chunk indices: chunk c covers row c>>2, k-offset (c&3)*8 (16B)
    const int c0 = wave * 128 + lane;          // instr 0
    const int c1 = c0 + 64;                    // instr 1
    const int r0 = c0 >> 2, k0off = (c0 & 3) * 8;
    const int r1 = c1 >> 2, k1off = (c1 & 3) * 8;
    unsigned short* ldsA0 = As + wave * 1024;
    unsigned short* ldsA1 = As + wave * 1024 + 512;
    unsigned short* ldsB0 = Bs + wave * 1024;
    unsigned short* ldsB1 = Bs + wave * 1024 + 512;

    floatx4 acc[4][4];
    #pragma unroll
    for (int i = 0; i < 4; ++i)
        #pragma unroll
        for (int j = 0; j < 4; ++j) acc[i][j] = (floatx4){0.f, 0.f, 0.f, 0.f};

    for (int kk = 0; kk < K; kk += 32) {
        g2l16(A + (size_t)(row0 + r0) * K + kk + k0off, ldsA0);
        g2l16(A + (size_t)(row0 + r1) * K + kk + k1off, ldsA1);
        g2l16(W + (size_t)(col0 + r0) * K + kk + k0off, ldsB0);
        g2l16(W + (size_t)(col0 + r1) * K + kk + k1off, ldsB1);
        __syncthreads();   // drains vmcnt before barrier

        short8 a[4], b[4];
        #pragma unroll
        for (int i = 0; i < 4; ++i)
            a[i] = *(const short8*)(As + (wr + i * 16 + ln) * 32 + qd * 8);
        #pragma unroll
        for (int j = 0; j < 4; ++j)
            b[j] = *(const short8*)(Bs + (wc + j * 16 + ln) * 32 + qd * 8);

        #pragma unroll
        for (int i = 0; i < 4; ++i)
            #pragma unroll
            for (int j = 0; j < 4; ++j)
                acc[i][j] = __builtin_amdgcn_mfma_f32_16x16x32_bf16(
                                a[i], b[j], acc[i][j], 0, 0, 0);
        __syncthreads();   // protect LDS from next iteration's staging
    }

    // epilogue: C/D layout col = lane&15, row = quad*4 + reg
    #pragma unroll
    for (int j = 0; j < 4; ++j) {
        const int col = col0 + wc + j * 16 + ln;
        float add = bias ? bias[col] : 0.f;
        float scale = 1.f, shift = 0.f;
        if (fuse_bn_relu) {
            scale = bn_g[col] * rsqrtf(bn_v[col] + 1e-5f);
            shift = bn_b[col] - bn_m[col] * scale;
        }
        #pragma unroll
        for (int i = 0; i < 4; ++i) {
            #pragma unroll
            for (int r = 0; r < 4; ++r) {
                const int row = row0 + wr + i * 16 + qd * 4 + r;
                float v = acc[i][j][r] + add;
                if (fuse_bn_relu) v = fmaxf(v * scale + shift, 0.f);
                if (Cf) Cf[(size_t)row * N + col] = v;
                if (Cb) Cb[(size_t)row * N + col] = f2bf(v);
            }
        }
    }
}

// ---------------------------------------------------------------------------
// fp32 -> bf16 conversions
// ---------------------------------------------------------------------------
__global__ __launch_bounds__(256)
void cvt_flat(const float* __restrict__ src, unsigned short* __restrict__ dst, int n4)
{
    int i = blockIdx.x * 256 + threadIdx.x;
    if (i < n4) {
        float4 v = ((const float4*)src)[i];
        ushort4 o;
        o.x = f2bf(v.x); o.y = f2bf(v.y); o.z = f2bf(v.z); o.w = f2bf(v.w);
        ((ushort4*)dst)[i] = o;
    }
}

__global__ __launch_bounds__(256)
void cvt_pad(const float* __restrict__ src, unsigned short* __restrict__ dst,
             int K, int Kp, int total)   // total = rows*Kp
{
    int i = blockIdx.x * 256 + threadIdx.x;
    if (i < total) {
        int r = i / Kp, c = i - r * Kp;
        dst[i] = (c < K) ? f2bf(src[(size_t)r * K + c]) : (unsigned short)0;
    }
}

// ---------------------------------------------------------------------------
// Fused attention (unchanged from round 1; ~1% of runtime)
// ---------------------------------------------------------------------------
__global__ __launch_bounds__(256)
void attn_kernel(const float* __restrict__ obj, const float* __restrict__ bbox,
                 const float* __restrict__ word, const float* __restrict__ sen,
                 const float* __restrict__ bod,
                 const float* __restrict__ Wc1, const float* __restrict__ Wc2,
                 const float* __restrict__ Wsa,
                 float* __restrict__ xsum_out)
{
    const int b = blockIdx.x;
    const int tid = threadIdx.x;

    __shared__ float xs[10][688];
    __shared__ float s0[688], s1[688];
    __shared__ float avec[10], mvec[10], att[10];
    __shared__ float cw[14], c1[50], c2[50];

    if (tid < 14) cw[tid] = Wsa[tid];
    if (tid < 50) { c1[tid] = Wc1[tid]; c2[tid] = Wc2[tid]; }

    for (int n = 0; n < 10; ++n) {
        const float* o  = obj  + ((size_t)b * 10 + n) * 128;
        const float* bx = bbox + ((size_t)b * 10 + n) * 4;
        const float* w  = word + ((size_t)b * 10 + n) * 300;
        const float* s  = sen  + ((size_t)b * 10 + n) * 128;
        const float* bo = bod  + (size_t)b * 128;
        for (int c = tid; c < 688; c += 256) {
            float v;
            if      (c < 128) v = o[c];
            else if (c < 132) v = bx[c - 128];
            else if (c < 432) v = w[c - 132];
            else if (c < 560) v = s[c - 432];
            else              v = bo[c - 560];
            xs[n][c] = v;
        }
    }
    __syncthreads();

    if (tid < 10) {
        float sm = 0.f, mx = -INFINITY;
        for (int c = 0; c < 688; ++c) {
            float v = xs[tid][c];
            sm += v; mx = fmaxf(mx, v);
        }
        avec[tid] = sm * (1.f / 688.f);
        mvec[tid] = mx;
    }
    __syncthreads();

    if (tid == 0) {
        float ha[5], hm[5];
        #pragma unroll
        for (int i = 0; i < 5; ++i) {
            float sa_ = 0.f, sm_ = 0.f;
            #pragma unroll
            for (int j = 0; j < 10; ++j) {
                sa_ += c1[i * 10 + j] * avec[j];
                sm_ += c1[i * 10 + j] * mvec[j];
            }
            ha[i] = fmaxf(sa_, 0.f);
            hm[i] = fmaxf(sm_, 0.f);
        }
        #pragma unroll
        for (int j = 0; j < 10; ++j) {
            float v = 0.f;
            #pragma unroll
            for (int i = 0; i < 5; ++i) v += c2[j * 5 + i] * (ha[i] + hm[i]);
            att[j] = 1.f / (1.f + expf(-v));
        }
    }
    __syncthreads();

    for (int c = tid; c < 688; c += 256) {
        float sm = 0.f, mx = -INFINITY;
        #pragma unroll
        for (int n = 0; n < 10; ++n) {
            float v = xs[n][c] * att[n];
            xs[n][c] = v;
            sm += v; mx = fmaxf(mx, v);
        }
        s0[c] = sm * 0.1f;
        s1[c] = mx;
    }
    __syncthreads();

    for (int c = tid; c < 688; c += 256) {
        float sa = 0.f;
        #pragma unroll
        for (int j = 0; j < 7; ++j) {
            int cc = c + j - 3;
            if (cc >= 0 && cc < 688)
                sa += cw[j] * s0[cc] + cw[7 + j] * s1[cc];
        }
        float sig = 1.f / (1.f + expf(-sa));
        float sm = 0.f;
        #pragma unroll
        for (int n = 0; n < 10; ++n) sm += xs[n][c];
        xsum_out[(size_t)b * 688 + c] = sm * sig;
    }
}

// ---------------------------------------------------------------------------
extern "C" void kernel_launch(void* const* d_in, const int* in_sizes, int n_in,
                              void* d_out, int out_size, void* d_ws, size_t ws_size,
                              hipStream_t stream)
{
    const float* f_obj = (const float*)d_in[0];
    const float* bbox  = (const float*)d_in[1];
    const float* word  = (const float*)d_in[2];
    const float* sent  = (const float*)d_in[3];
    const float* body  = (const float*)d_in[4];
    const float* W1_o  = (const float*)d_in[5];
    const float* g_o = (const float*)d_in[6],  *b_o = (const float*)d_in[7];
    const float* m_o = (const float*)d_in[8],  *v_o = (const float*)d_in[9];
    const float* W2_o  = (const float*)d_in[10];
    const float* W1_s  = (const float*)d_in[11];
    const float* g_s = (const float*)d_in[12], *b_s = (const float*)d_in[13];
    const float* m_s = (const float*)d_in[14], *v_s = (const float*)d_in[15];
    const float* W2_s  = (const float*)d_in[16];
    const float* W1_b  = (const float*)d_in[17];
    const float* g_b = (const float*)d_in[18], *b_b = (const float*)d_in[19];
    const float* m_b = (const float*)d_in[20], *v_b = (const float*)d_in[21];
    const float* W2_b  = (const float*)d_in[22];
    const float* Wc1 = (const float*)d_in[23];
    const float* Wc2 = (const float*)d_in[24];
    const float* Wsa = (const float*)d_in[25];
    const float* Wf  = (const float*)d_in[26];
    const float* bf  = (const float*)d_in[27];
    const float* g_f = (const float*)d_in[28], *b_f = (const float*)d_in[29];
    const float* m_f = (const float*)d_in[30], *v_f = (const float*)d_in[31];
    float* out = (float*)d_out;

    // ---- workspace carve (all sizes multiple of 256 B); total 115,736,576 B
    char* p = (char*)d_ws;
    unsigned short* convA   = (unsigned short*)p; p += 83886080;  // 10240*4096 bf16 (reused 3x)
    unsigned short* w1s     = (unsigned short*)p; p += 4194304;   // 512*4096
    unsigned short* w2s     = (unsigned short*)p; p += 131072;    // 128*512
    unsigned short* w1o     = (unsigned short*)p; p += 262144;    // 128*1024
    unsigned short* w2o     = (unsigned short*)p; p += 32768;     // 128*128
    unsigned short* w1b     = (unsigned short*)p; p += 1048576;   // 256*2048
    unsigned short* w2b     = (unsigned short*)p; p += 65536;     // 128*256
    unsigned short* wfp     = (unsigned short*)p; p += 360448;    // 256*704 (padded)
    unsigned short* h_bf    = (unsigned short*)p; p += 10485760;  // 10240*512 (reused 3x)
    float*          sen_f   = (float*)p;          p += 5242880;   // 10240*128
    float*          obj_f   = (float*)p;          p += 5242880;   // 10240*128
    float*          bod_f   = (float*)p;          p += 524288;    // 1024*128
    float*          xsum_f  = (float*)p;          p += 2818048;   // 1024*688
    unsigned short* xsum_bf = (unsigned short*)p; p += 1441792;   // 1024*704 (padded)
    if ((size_t)(p - (char*)d_ws) > ws_size) return;  // ws too small -> visible failure

    #define CVT(src, dst, n) cvt_flat<<<((n)/4 + 255)/256, 256, 0, stream>>>(src, dst, (n)/4)

    // weights -> bf16 (once per launch; cheap)
    CVT(W1_s, w1s, 512 * 4096);
    CVT(W2_s, w2s, 128 * 512);
    CVT(W1_o, w1o, 128 * 1024);
    CVT(W2_o, w2o, 128 * 128);
    CVT(W1_b, w1b, 256 * 2048);
    CVT(W2_b, w2b, 128 * 256);
    cvt_pad<<<(256 * 704 + 255)/256, 256, 0, stream>>>(Wf, wfp, 688, 704, 256 * 704);

    // ---- sentiment MLP: 4096 -> 512 (BN+ReLU, bf16 out) -> 128 (fp32 out)
    CVT(sent, convA, 10240 * 4096);
    gemm_mfma<<<dim3(512/128, 10240/128), 256, 0, stream>>>(
        convA, w1s, 10240, 512, 4096, nullptr, h_bf, nullptr, g_s, b_s, m_s, v_s, 1);
    gemm_mfma<<<dim3(128/128, 10240/128), 256, 0, stream>>>(
        h_bf, w2s, 10240, 128, 512, sen_f, nullptr, nullptr, nullptr, nullptr, nullptr, nullptr, 0);

    // ---- object MLP: 1024 -> 128 -> 128
    CVT(f_obj, convA, 10240 * 1024);
    gemm_mfma<<<dim3(128/128, 10240/128), 256, 0, stream>>>(
        convA, w1o, 10240, 128, 1024, nullptr, h_bf, nullptr, g_o, b_o, m_o, v_o, 1);
    gemm_mfma<<<dim3(128/128, 10240/128), 256, 0, stream>>>(
        h_bf, w2o, 10240, 128, 128, obj_f, nullptr, nullptr, nullptr, nullptr, nullptr, nullptr, 0);

    // ---- body MLP: 2048 -> 256 -> 128  (per-B)
    CVT(body, convA, 1024 * 2048);
    gemm_mfma<<<dim3(256/128, 1024/128), 256, 0, stream>>>(
        convA, w1b, 1024, 256, 2048, nullptr, h_bf, nullptr, g_b, b_b, m_b, v_b, 1);
    gemm_mfma<<<dim3(128/128, 1024/128), 256, 0, stream>>>(
        h_bf, w2b, 1024, 128, 256, bod_f, nullptr, nullptr, nullptr, nullptr, nullptr, nullptr, 0);

    // ---- fused attention + sum over N
    attn_kernel<<<1024, 256, 0, stream>>>(obj_f, bbox, word, sen_f, bod_f,
                                          Wc1, Wc2, Wsa, xsum_f);

    // ---- fc1 (+bias, BN, ReLU): K=688 zero-padded to 704
    cvt_pad<<<(1024 * 704 + 255)/256, 256, 0, stream>>>(xsum_f, xsum_bf, 688, 704, 1024 * 704);
    gemm_mfma<<<dim3(256/128, 1024/128), 256, 0, stream>>>(
        xsum_bf, wfp, 1024, 256, 704, out, nullptr, bf, g_f, b_f, m_f, v_f, 1);

    #undef CVT
}

// Round 3
// 539.002 us; speedup vs baseline: 2.2318x; 1.2096x over previous
//
#include <hip/hip_runtime.h>
#include <hip/hip_bf16.h>
#include <math.h>

typedef __attribute__((ext_vector_type(8))) short short8;   // 8 x bf16 (4 VGPRs)
typedef __attribute__((ext_vector_type(4))) float floatx4;  // MFMA C/D frag

static __device__ __forceinline__ unsigned short f2bf(float f) {
    unsigned int u = __float_as_uint(f);
    unsigned int r = (u + 0x7fffu + ((u >> 16) & 1u)) >> 16;   // RNE
    return (unsigned short)r;
}

// async 16B global -> LDS copy (lds dest = wave-uniform base + lane*16)
static __device__ __forceinline__ void g2l16(const void* g, void* l) {
    __builtin_amdgcn_global_load_lds(
        (const __attribute__((address_space(1))) unsigned int*)g,
        (__attribute__((address_space(3))) unsigned int*)l,
        16, 0, 0);
}

// ---------------------------------------------------------------------------
// Grouped bf16 MFMA GEMM, double-buffered.
//   C[M,N] = A[M,K] @ W[N,K]^T
// A either fp32 (converted during staging, with K zero-pad support) or bf16
// (async g2l16 path). W always bf16 (pre-converted). Epilogue: optional bias
// + BN + ReLU; writes fp32 (Cf) and/or bf16 (Cb).
// Tiles: 128x128, 4 waves, each wave a 64x64 quadrant of 16x16x32 MFMAs.
// ---------------------------------------------------------------------------
struct GDesc {
    const float*          Af;    // fp32 A (or null)
    const unsigned short* Ab;    // bf16 A (or null)
    const unsigned short* W;     // bf16 W, row stride = K
    float*          Cf;          // fp32 out (or null)
    unsigned short* Cb;          // bf16 out (or null)
    const float *bias, *g, *b, *m, *v;
    int M, N, K;                 // K = padded to mult of 32 (W stride, LDS tiles)
    int Kreal;                   // A row stride / true K (= K unless padded)
    int fuse;                    // 1: BN+ReLU
    int nbx;                     // N / 128
    int block0;                  // first flat block id of this group
};
struct GArgs { GDesc g[3]; int n; };

__global__ __launch_bounds__(256)
void gemm_grouped(GArgs ga)
{
    __shared__ unsigned short As[2][4096];   // 128 rows x 32 k (bf16)
    __shared__ unsigned short Bs[2][4096];

    const int bid = blockIdx.x;
    int gi = 0;
    #pragma unroll
    for (int i = 1; i < 3; ++i)
        if (i < ga.n && bid >= ga.g[i].block0) gi = i;
    const GDesc d = ga.g[gi];
    const int local = bid - d.block0;
    const int bx = local % d.nbx;
    const int by = local / d.nbx;
    const int row0 = by * 128;
    const int col0 = bx * 128;

    const int tid  = threadIdx.x;
    const int wave = tid >> 6;
    const int lane = tid & 63;
    const int qd   = lane >> 4;
    const int ln   = lane & 15;
    const int wr   = (wave >> 1) * 64;
    const int wc   = (wave & 1) * 64;

    // g2l16 chunk mapping: chunk c -> row c>>2, k-offset (c&3)*8
    const int c0 = wave * 128 + lane;
    const int c1 = c0 + 64;
    const int r0 = c0 >> 2, k0 = (c0 & 3) * 8;
    const int r1 = c1 >> 2, k1 = (c1 & 3) * 8;

    // fp32 staging mapping: pass p covers rows p*32..p*32+31
    const int sr = tid >> 3;          // 0..31
    const int sc = (tid & 7) * 4;     // 0,4,..,28

    const bool afp = (d.Af != nullptr);
    const int niter = d.K >> 5;

    floatx4 acc[4][4];
    #pragma unroll
    for (int i = 0; i < 4; ++i)
        #pragma unroll
        for (int j = 0; j < 4; ++j) acc[i][j] = (floatx4){0.f, 0.f, 0.f, 0.f};

    // ---- prologue: stage tile 0 into buffer 0 ----
    g2l16(d.W + (size_t)(col0 + r0) * d.K + k0, &Bs[0][(size_t)wave * 1024]);
    g2l16(d.W + (size_t)(col0 + r1) * d.K + k1, &Bs[0][(size_t)wave * 1024 + 512]);
    if (afp) {
        #pragma unroll
        for (int p = 0; p < 4; ++p) {
            float4 v = (sc < d.Kreal)
                ? *(const float4*)(d.Af + (size_t)(row0 + p * 32 + sr) * d.Kreal + sc)
                : (float4){0.f, 0.f, 0.f, 0.f};
            ushort4 o = { f2bf(v.x), f2bf(v.y), f2bf(v.z), f2bf(v.w) };
            *(ushort4*)&As[0][(p * 32 + sr) * 32 + sc] = o;
        }
    } else {
        g2l16(d.Ab + (size_t)(row0 + r0) * d.K + k0, &As[0][(size_t)wave * 1024]);
        g2l16(d.Ab + (size_t)(row0 + r1) * d.K + k1, &As[0][(size_t)wave * 1024 + 512]);
    }
    __syncthreads();

    int cur = 0;
    for (int it = 0; it < niter; ++it) {
        const int kk = it * 32;
        const int nxt = cur ^ 1;
        const bool pf = (it + 1 < niter);

        float4 areg[4];
        if (pf) {
            const int kn = kk + 32;
            g2l16(d.W + (size_t)(col0 + r0) * d.K + kn + k0, &Bs[nxt][(size_t)wave * 1024]);
            g2l16(d.W + (size_t)(col0 + r1) * d.K + kn + k1, &Bs[nxt][(size_t)wave * 1024 + 512]);
            if (afp) {
                #pragma unroll
                for (int p = 0; p < 4; ++p)
                    areg[p] = (kn + sc < d.Kreal)
                        ? *(const float4*)(d.Af + (size_t)(row0 + p * 32 + sr) * d.Kreal + kn + sc)
                        : (float4){0.f, 0.f, 0.f, 0.f};
            } else {
                g2l16(d.Ab + (size_t)(row0 + r0) * d.K + kn + k0, &As[nxt][(size_t)wave * 1024]);
                g2l16(d.Ab + (size_t)(row0 + r1) * d.K + kn + k1, &As[nxt][(size_t)wave * 1024 + 512]);
            }
        }

        // ---- compute on current buffer ----
        short8 a[4], b[4];
        #pragma unroll
        for (int i = 0; i < 4; ++i)
            a[i] = *(const short8*)&As[cur][(wr + i * 16 + ln) * 32 + qd * 8];
        #pragma unroll
        for (int j = 0; j < 4; ++j)
            b[j] = *(const short8*)&Bs[cur][(wc + j * 16 + ln) * 32 + qd * 8];
        #pragma unroll
        for (int i = 0; i < 4; ++i)
            #pragma unroll
            for (int j = 0; j < 4; ++j)
                acc[i][j] = __builtin_amdgcn_mfma_f32_16x16x32_bf16(
                                a[i], b[j], acc[i][j], 0, 0, 0);

        if (pf && afp) {
            #pragma unroll
            for (int p = 0; p < 4; ++p) {
                ushort4 o = { f2bf(areg[p].x), f2bf(areg[p].y),
                              f2bf(areg[p].z), f2bf(areg[p].w) };
                *(ushort4*)&As[nxt][(p * 32 + sr) * 32 + sc] = o;
            }
        }
        __syncthreads();
        cur = nxt;
    }

    // ---- epilogue: C/D layout col = lane&15, row = quad*4 + reg ----
    #pragma unroll
    for (int j = 0; j < 4; ++j) {
        const int col = col0 + wc + j * 16 + ln;
        float add = d.bias ? d.bias[col] : 0.f;
        float scale = 1.f, shift = 0.f;
        if (d.fuse) {
            scale = d.g[col] * rsqrtf(d.v[col] + 1e-5f);
            shift = d.b[col] - d.m[col] * scale;
        }
        #pragma unroll
        for (int i = 0; i < 4; ++i) {
            #pragma unroll
            for (int r = 0; r < 4; ++r) {
                const int row = row0 + wr + i * 16 + qd * 4 + r;
                float vv = acc[i][j][r] + add;
                if (d.fuse) vv = fmaxf(vv * scale + shift, 0.f);
                if (d.Cf) d.Cf[(size_t)row * d.N + col] = vv;
                if (d.Cb) d.Cb[(size_t)row * d.N + col] = f2bf(vv);
            }
        }
    }
}

// ---------------------------------------------------------------------------
// One-shot weight conversion: all 7 weight matrices fp32 -> bf16 (fc padded)
// ---------------------------------------------------------------------------
struct WSeg { const float* src; unsigned short* dst; int Kreal; int Kp; };
struct WArgs { WSeg s[7]; int off[8]; };

__global__ __launch_bounds__(256)
void cvt_weights(WArgs wa)
{
    int i = blockIdx.x * 256 + threadIdx.x;
    if (i >= wa.off[7]) return;
    int s = 0;
    #pragma unroll
    for (int j = 1; j < 7; ++j) if (i >= wa.off[j]) s = j;
    const WSeg sg = wa.s[s];
    const int li = i - wa.off[s];
    const int r = li / sg.Kp, c = li - r * sg.Kp;
    sg.dst[li] = (c < sg.Kreal) ? f2bf(sg.src[(size_t)r * sg.Kreal + c])
                                : (unsigned short)0;
}

// ---------------------------------------------------------------------------
// Fused attention (per batch row): channel attn (N=10) + spatial conv k=7 +
// weighted sum over N -> xsum[b][688]
// ---------------------------------------------------------------------------
__global__ __launch_bounds__(256)
void attn_kernel(const float* __restrict__ obj, const float* __restrict__ bbox,
                 const float* __restrict__ word, const float* __restrict__ sen,
                 const float* __restrict__ bod,
                 const float* __restrict__ Wc1, const float* __restrict__ Wc2,
                 const float* __restrict__ Wsa,
                 float* __restrict__ xsum_out)
{
    const int b = blockIdx.x;
    const int tid = threadIdx.x;

    __shared__ float xs[10][688];
    __shared__ float s0[688], s1[688];
    __shared__ float avec[10], mvec[10], att[10];
    __shared__ float cw[14], c1[50], c2[50];

    if (tid < 14) cw[tid] = Wsa[tid];
    if (tid < 50) { c1[tid] = Wc1[tid]; c2[tid] = Wc2[tid]; }

    for (int n = 0; n < 10; ++n) {
        const float* o  = obj  + ((size_t)b * 10 + n) * 128;
        const float* bx = bbox + ((size_t)b * 10 + n) * 4;
        const float* w  = word + ((size_t)b * 10 + n) * 300;
        const float* s  = sen  + ((size_t)b * 10 + n) * 128;
        const float* bo = bod  + (size_t)b * 128;
        for (int c = tid; c < 688; c += 256) {
            float v;
            if      (c < 128) v = o[c];
            else if (c < 132) v = bx[c - 128];
            else if (c < 432) v = w[c - 132];
            else if (c < 560) v = s[c - 432];
            else              v = bo[c - 560];
            xs[n][c] = v;
        }
    }
    __syncthreads();

    if (tid < 10) {
        float sm = 0.f, mx = -INFINITY;
        for (int c = 0; c < 688; ++c) {
            float v = xs[tid][c];
            sm += v; mx = fmaxf(mx, v);
        }
        avec[tid] = sm * (1.f / 688.f);
        mvec[tid] = mx;
    }
    __syncthreads();

    if (tid == 0) {
        float ha[5], hm[5];
        #pragma unroll
        for (int i = 0; i < 5; ++i) {
            float sa_ = 0.f, sm_ = 0.f;
            #pragma unroll
            for (int j = 0; j < 10; ++j) {
                sa_ += c1[i * 10 + j] * avec[j];
                sm_ += c1[i * 10 + j] * mvec[j];
            }
            ha[i] = fmaxf(sa_, 0.f);
            hm[i] = fmaxf(sm_, 0.f);
        }
        #pragma unroll
        for (int j = 0; j < 10; ++j) {
            float v = 0.f;
            #pragma unroll
            for (int i = 0; i < 5; ++i) v += c2[j * 5 + i] * (ha[i] + hm[i]);
            att[j] = 1.f / (1.f + expf(-v));
        }
    }
    __syncthreads();

    for (int c = tid; c < 688; c += 256) {
        float sm = 0.f, mx = -INFINITY;
        #pragma unroll
        for (int n = 0; n < 10; ++n) {
            float v = xs[n][c] * att[n];
            xs[n][c] = v;
            sm += v; mx = fmaxf(mx, v);
        }
        s0[c] = sm * 0.1f;
        s1[c] = mx;
    }
    __syncthreads();

    for (int c = tid; c < 688; c += 256) {
        float sa = 0.f;
        #pragma unroll
        for (int j = 0; j < 7; ++j) {
            int cc = c + j - 3;
            if (cc >= 0 && cc < 688)
                sa += cw[j] * s0[cc] + cw[7 + j] * s1[cc];
        }
        float sig = 1.f / (1.f + expf(-sa));
        float sm = 0.f;
        #pragma unroll
        for (int n = 0; n < 10; ++n) sm += xs[n][c];
        xsum_out[(size_t)b * 688 + c] = sm * sig;
    }
}

// ---------------------------------------------------------------------------
extern "C" void kernel_launch(void* const* d_in, const int* in_sizes, int n_in,
                              void* d_out, int out_size, void* d_ws, size_t ws_size,
                              hipStream_t stream)
{
    const float* f_obj = (const float*)d_in[0];
    const float* bbox  = (const float*)d_in[1];
    const float* word  = (const float*)d_in[2];
    const float* sent  = (const float*)d_in[3];
    const float* body  = (const float*)d_in[4];
    const float* W1_o  = (const float*)d_in[5];
    const float* g_o = (const float*)d_in[6],  *b_o = (const float*)d_in[7];
    const float* m_o = (const float*)d_in[8],  *v_o = (const float*)d_in[9];
    const float* W2_o  = (const float*)d_in[10];
    const float* W1_s  = (const float*)d_in[11];
    const float* g_s = (const float*)d_in[12], *b_s = (const float*)d_in[13];
    const float* m_s = (const float*)d_in[14], *v_s = (const float*)d_in[15];
    const float* W2_s  = (const float*)d_in[16];
    const float* W1_b  = (const float*)d_in[17];
    const float* g_b = (const float*)d_in[18], *b_b = (const float*)d_in[19];
    const float* m_b = (const float*)d_in[20], *v_b = (const float*)d_in[21];
    const float* W2_b  = (const float*)d_in[22];
    const float* Wc1 = (const float*)d_in[23];
    const float* Wc2 = (const float*)d_in[24];
    const float* Wsa = (const float*)d_in[25];
    const float* Wf  = (const float*)d_in[26];
    const float* bf  = (const float*)d_in[27];
    const float* g_f = (const float*)d_in[28], *b_f = (const float*)d_in[29];
    const float* m_f = (const float*)d_in[30], *v_f = (const float*)d_in[31];
    float* out = (float*)d_out;

    // ---- workspace carve; total ~33.6 MB ----
    char* p = (char*)d_ws;
    unsigned short* w1s = (unsigned short*)p; p += 4194304;   // 512*4096
    unsigned short* w2s = (unsigned short*)p; p += 131072;    // 128*512
    unsigned short* w1o = (unsigned short*)p; p += 262144;    // 128*1024
    unsigned short* w2o = (unsigned short*)p; p += 32768;     // 128*128
    unsigned short* w1b = (unsigned short*)p; p += 1048576;   // 256*2048
    unsigned short* w2b = (unsigned short*)p; p += 65536;     // 128*256
    unsigned short* wfp = (unsigned short*)p; p += 360448;    // 256*704 padded
    unsigned short* h_s = (unsigned short*)p; p += 10485760;  // 10240*512
    unsigned short* h_o = (unsigned short*)p; p += 2621440;   // 10240*128
    unsigned short* h_b = (unsigned short*)p; p += 524288;    // 1024*256
    float* sen_f  = (float*)p; p += 5242880;                  // 10240*128
    float* obj_f  = (float*)p; p += 5242880;                  // 10240*128
    float* bod_f  = (float*)p; p += 524288;                   // 1024*128
    float* xsum_f = (float*)p; p += 2818048;                  // 1024*688
    if ((size_t)(p - (char*)d_ws) > ws_size) return;

    // ---- 1) weights -> bf16 in one launch ----
    WArgs wa;
    wa.s[0] = { W1_s, w1s, 4096, 4096 };
    wa.s[1] = { W2_s, w2s,  512,  512 };
    wa.s[2] = { W1_o, w1o, 1024, 1024 };
    wa.s[3] = { W2_o, w2o,  128,  128 };
    wa.s[4] = { W1_b, w1b, 2048, 2048 };
    wa.s[5] = { W2_b, w2b,  256,  256 };
    wa.s[6] = { Wf,   wfp,  688,  704 };
    const int wn[7] = { 512*4096, 128*512, 128*1024, 128*128, 256*2048, 128*256, 256*704 };
    wa.off[0] = 0;
    for (int i = 0; i < 7; ++i) wa.off[i + 1] = wa.off[i] + wn[i];
    cvt_weights<<<(wa.off[7] + 255) / 256, 256, 0, stream>>>(wa);

    // ---- 2) stage-1 grouped GEMM (fp32 A fused-convert; BN+ReLU; bf16 out) ----
    {
        GArgs ga; ga.n = 3;
        ga.g[0] = { sent,  nullptr, w1s, nullptr, h_s, nullptr, g_s, b_s, m_s, v_s,
                    10240, 512, 4096, 4096, 1, 4, 0 };
        ga.g[1] = { f_obj, nullptr, w1o, nullptr, h_o, nullptr, g_o, b_o, m_o, v_o,
                    10240, 128, 1024, 1024, 1, 1, 320 };
        ga.g[2] = { body,  nullptr, w1b, nullptr, h_b, nullptr, g_b, b_b, m_b, v_b,
                    1024, 256, 2048, 2048, 1, 2, 400 };
        gemm_grouped<<<416, 256, 0, stream>>>(ga);
    }

    // ---- 3) stage-2 grouped GEMM (bf16 A; fp32 out) ----
    {
        GArgs ga; ga.n = 3;
        ga.g[0] = { nullptr, h_s, w2s, sen_f, nullptr, nullptr, nullptr, nullptr, nullptr, nullptr,
                    10240, 128, 512, 512, 0, 1, 0 };
        ga.g[1] = { nullptr, h_o, w2o, obj_f, nullptr, nullptr, nullptr, nullptr, nullptr, nullptr,
                    10240, 128, 128, 128, 0, 1, 80 };
        ga.g[2] = { nullptr, h_b, w2b, bod_f, nullptr, nullptr, nullptr, nullptr, nullptr, nullptr,
                    1024, 128, 256, 256, 0, 1, 160 };
        gemm_grouped<<<168, 256, 0, stream>>>(ga);
    }

    // ---- 4) fused attention + sum over N ----
    attn_kernel<<<1024, 256, 0, stream>>>(obj_f, bbox, word, sen_f, bod_f,
                                          Wc1, Wc2, Wsa, xsum_f);

    // ---- 5) fc1 (+bias, BN, ReLU), K=688 zero-padded to 704 in staging ----
    {
        GArgs ga; ga.n = 1;
        ga.g[0] = { xsum_f, nullptr, wfp, out, nullptr, bf, g_f, b_f, m_f, v_f,
                    1024, 256, 704, 688, 1, 2, 0 };
        gemm_grouped<<<16, 256, 0, stream>>>(ga);
    }
}